// Round 13
// baseline (381.107 us; speedup 1.0000x reference)
//
#include <hip/hip_runtime.h>
#include <hip/hip_bf16.h>

typedef __hip_bfloat16 bf16;

#define BB 32   // batch
#define NN 16   // patches / backbones
#define NSH 16  // stats-accumulator shards (atomic contention /16)

using bf16x8v = __attribute__((ext_vector_type(8))) short;  // 8 bf16 (4 VGPRs)
using f32x4v  = __attribute__((ext_vector_type(4))) float;  // 4 fp32

__device__ __forceinline__ float b2f(bf16 v){ return __bfloat162float(v); }
__device__ __forceinline__ bf16  f2b(float v){ return __float2bfloat16(v); }
__device__ __forceinline__ float bfbits2f(unsigned int h){
    unsigned int x = h << 16; float f; __builtin_memcpy(&f, &x, 4); return f;
}
__device__ __forceinline__ unsigned bbits(float f){
    bf16 h = f2b(f); unsigned short u; __builtin_memcpy(&u, &h, 2); return (unsigned)u;
}
__device__ __forceinline__ bf16x8v pack8(float4 a, float4 b){
    bf16x8v r;
    r[0] = (short)bbits(a.x); r[1] = (short)bbits(a.y);
    r[2] = (short)bbits(a.z); r[3] = (short)bbits(a.w);
    r[4] = (short)bbits(b.x); r[5] = (short)bbits(b.y);
    r[6] = (short)bbits(b.z); r[7] = (short)bbits(b.w);
    return r;
}

// ---------------------------------------------------------------------------
// dtype probe: flag=1 -> float32 inputs; 0 -> bf16. (32 blocks, uint4 loads)
// ---------------------------------------------------------------------------
__launch_bounds__(256)
__global__ void detect_ker(const uint4* __restrict__ xs, int* __restrict__ flag)
{
    const int base = blockIdx.x * 1024 + threadIdx.x;
    int cnt = 0;
    #pragma unroll
    for (int k = 0; k < 4; ++k) {
        uint4 v = xs[base + k * 256];
        unsigned w[4] = {v.x, v.y, v.z, v.w};
        #pragma unroll
        for (int p = 0; p < 4; ++p) {
            if ((w[p] & 0x7F80u) == 0x7F80u) cnt++;
            if (((w[p] >> 16) & 0x7F80u) == 0x7F80u) cnt++;
        }
    }
    unsigned long long m = __ballot(cnt != 0);
    if ((threadIdx.x & 63) == 0 && m != 0ull) atomicOr(flag, 1);
}

// ---------------------------------------------------------------------------
// stage all inputs into a contiguous FLOAT arena
// ---------------------------------------------------------------------------
struct CvtArgs { const void* src[19]; int cnt[19]; int off[19]; };

__launch_bounds__(256)
__global__ void convert_ker(CvtArgs a, float* __restrict__ dst, const int* __restrict__ flag)
{
    const int which = blockIdx.y;
    const int cnt = a.cnt[which];
    if ((int)blockIdx.x * 2048 >= cnt) return;
    const int base = blockIdx.x * 2048 + threadIdx.x;
    float* d = dst + a.off[which];
    if (*flag) {
        const float* s = (const float*)a.src[which];
        #pragma unroll
        for (int k = 0; k < 8; ++k) { int j = base + k * 256; if (j < cnt) d[j] = s[j]; }
    } else {
        const bf16* s = (const bf16*)a.src[which];
        #pragma unroll
        for (int k = 0; k < 8; ++k) { int j = base + k * 256; if (j < cnt) d[j] = b2f(s[j]); }
    }
}

// ---------------------------------------------------------------------------
// weight prep for MFMA convs: f32 [n][co][ci][3][3] -> bf16 B-fragment layout
// ---------------------------------------------------------------------------
struct WpArgs { const float* src[5]; bf16* dst[5]; int cout[5]; int cin[5]; int nk[5]; int tot[5]; };

__launch_bounds__(256)
__global__ void wprep_ker(WpArgs a)
{
    const int stg = blockIdx.y;
    const int cout = a.cout[stg], cin = a.cin[stg], nk = a.nk[stg];
    int idx = blockIdx.x * 256 + threadIdx.x;
    if (idx >= a.tot[stg]) return;
    int j  = idx & 7;
    int co = (idx >> 3) % cout;
    int rest = (idx >> 3) / cout;      // = (n*nk + c)*4 + k8
    int k8 = rest & 3;
    int cn = rest >> 2;                // n*nk + c
    int c  = cn % nk;
    int n  = cn / nk;
    int k  = c * 32 + k8 * 8 + j;
    int tap = k / cin;
    int ci  = k - tap * cin;
    float v = 0.f;
    if (tap < 9) v = a.src[stg][((size_t)(n * cout + co) * cin + ci) * 9 + tap];
    a.dst[stg][idx] = f2b(v);
}

// ---------------------------------------------------------------------------
// conv0 (VERIFIED VALU path): x -> a0 NHWC bf16 + sharded stats atomics.
// conv0 arithmetic is FROZEN (absmax 0.2969 vs 0.30; R8/R9 showed any
// numerics change crosses the boundary). XCD-chunked block swizzle only.
// ---------------------------------------------------------------------------
__launch_bounds__(256)
__global__ void conv0w_ker(const float* __restrict__ x, const float* __restrict__ w,
                           bf16* __restrict__ a0, float* __restrict__ accum)
{
    constexpr int STRIP = 8, STRIPS = 8, IN_ROWS = 10, TW = 66;
    constexpr int G = NN * BB * STRIPS;
    __shared__ float tile[3][IN_ROWS][TW];    // 7920 B
    const int tid = threadIdx.x;
    const int bid = (blockIdx.x & 7) * (G >> 3) + (blockIdx.x >> 3);  // XCD-chunked
    const int st = bid % STRIPS;
    const int b = (bid / STRIPS) % BB;
    const int n = bid / (STRIPS * BB);
    const int pr = (n >> 2) * 64, pc = (n & 3) * 64;
    const int r0 = st * STRIP - 1;

    for (int idx = tid; idx < 3 * IN_ROWS * TW; idx += 256) {
        int ci = idx / (IN_ROWS * TW);
        int rem = idx - ci * (IN_ROWS * TW);
        int rr = rem / TW, cc = rem - rr * TW;
        int gr = r0 + rr, gc = cc - 1;
        float v = 0.f;
        if (gr >= 0 && gr < 64 && gc >= 0 && gc < 64)
            v = x[((size_t)(b * 3 + ci) * 256 + (pr + gr)) * 256 + (pc + gc)];
        tile[ci][rr][cc] = v;
    }
    __syncthreads();

    const int xo = tid & 63;
    const int wv = tid >> 6;
    const int co0 = wv * 4;
    const float* wb = w + __builtin_amdgcn_readfirstlane((n * 16 + co0) * 27);

    float acc[4][STRIP];
    #pragma unroll
    for (int t = 0; t < 4; ++t)
        #pragma unroll
        for (int r = 0; r < STRIP; ++r) acc[t][r] = 0.f;

    #pragma unroll
    for (int ci = 0; ci < 3; ++ci) {
        float wr[4][9];
        #pragma unroll
        for (int t = 0; t < 4; ++t)
            #pragma unroll
            for (int j = 0; j < 9; ++j)
                wr[t][j] = wb[t * 27 + ci * 9 + j];
        float win[3][3];
        #pragma unroll
        for (int c0 = 0; c0 < 3; ++c0) {
            win[0][c0] = tile[ci][0][xo + c0];
            win[1][c0] = tile[ci][1][xo + c0];
        }
        #pragma unroll
        for (int ry = 0; ry < STRIP; ++ry) {
            #pragma unroll
            for (int c0 = 0; c0 < 3; ++c0)
                win[(ry + 2) % 3][c0] = tile[ci][ry + 2][xo + c0];
            #pragma unroll
            for (int ky = 0; ky < 3; ++ky)
                #pragma unroll
                for (int kx = 0; kx < 3; ++kx) {
                    float v = win[(ry + ky) % 3][kx];
                    #pragma unroll
                    for (int t = 0; t < 4; ++t)
                        acc[t][ry] = fmaf(v, wr[t][ky * 3 + kx], acc[t][ry]);
                }
        }
    }

    // direct NHWC packed store: 4 couts = 8B per (pixel, wave)
    bf16* ab = a0 + (size_t)(n * BB + b) * 65536 + (size_t)st * 8192;
    #pragma unroll
    for (int r = 0; r < STRIP; ++r) {
        uint2 pk;
        pk.x = (bbits(acc[1][r]) << 16) | bbits(acc[0][r]);
        pk.y = (bbits(acc[3][r]) << 16) | bbits(acc[2][r]);
        *(uint2*)&ab[(size_t)(r * 64 + xo) * 16 + co0] = pk;
    }

    // stats
    float s[4], q[4];
    #pragma unroll
    for (int t = 0; t < 4; ++t) {
        s[t] = 0.f; q[t] = 0.f;
        #pragma unroll
        for (int r = 0; r < STRIP; ++r) {
            s[t] += acc[t][r];
            q[t] = fmaf(acc[t][r], acc[t][r], q[t]);
        }
    }
    #pragma unroll
    for (int off = 32; off > 0; off >>= 1) {
        #pragma unroll
        for (int t = 0; t < 4; ++t) {
            s[t] += __shfl_down(s[t], off, 64);
            q[t] += __shfl_down(q[t], off, 64);
        }
    }
    if (xo == 0) {
        float* As = accum + (bid & (NSH - 1)) * (2 * NN * 16);
        #pragma unroll
        for (int t = 0; t < 4; ++t) {
            atomicAdd(&As[n * 16 + co0 + t],           s[t]);
            atomicAdd(&As[256 + n * 16 + co0 + t], q[t]);
        }
    }
}

// ---------------------------------------------------------------------------
// fused herpn + 3x3 conv via MFMA implicit GEMM (NHWC bf16 activations).
// R13: stages 3/4 get the R12-validated stage-5 treatment (KCH=3, MINW=3,
// SPLITNT). Numerics bitwise-stable: per-accumulator MFMA order unchanged,
// per-shard stats terms identical (only atomic order changes — R10-proven).
// Stages 1-2 use <...,0,1,false> = original codegen.
// ---------------------------------------------------------------------------
template<int CIN, int COUT, int WIN, int STRIDE, int RB, int KCH, int MINW, bool SPLITNT>
__launch_bounds__(256, MINW)
__global__ void mconv_ker(const bf16* __restrict__ ain, const float* __restrict__ aprev,
                          const float* __restrict__ hw, const bf16* __restrict__ wt,
                          bf16* __restrict__ aout, float* __restrict__ accum)
{
    constexpr int HIN = WIN;
    constexpr int WOUT = WIN / STRIDE, HOUT = WIN / STRIDE;
    constexpr int CIN8 = CIN / 8;                 // 16B chunks per pixel
    constexpr int XS = WIN + 2;                   // x slots incl halo cols
    constexpr int IN_ROWS = STRIDE * (RB - 1) + 3;
    constexpr int STRIPS = HOUT / RB;
    constexpr int G = NN * BB * STRIPS;           // x-grid size (divisible by 8)
    constexpr int NK = (CIN == 16) ? 5 : (9 * CIN) / 32;   // K chunks of 32
    constexpr int NT = COUT / 16;                 // N tiles
    constexpr int MT = RB * (WOUT / 16);          // M tiles per block
    constexpr int MW = MT / 4;                    // M tiles per wave
    constexpr int SW = (CIN8 == 2) ? 2 : ((CIN8 == 4) ? 1 : 0);
    constexpr int SM = CIN8 - 1;
    static_assert(MT % 4 == 0, "4 waves");
    static_assert(G % 8 == 0, "bijective XCD swizzle");
    static_assert(KCH == 0 || NK % KCH == 0, "K chunking divides NK");

    __shared__ __align__(16) short tile[IN_ROWS * XS * CIN8 * 8];
    __shared__ float cfA[CIN], cfB[CIN], cfC[CIN];
    __shared__ float sred[2][COUT];

    const int tid = threadIdx.x;
    const int bid = (blockIdx.x & 7) * (G >> 3) + (blockIdx.x >> 3);  // XCD-chunked
    const int st = bid % STRIPS;
    const int b = (bid / STRIPS) % BB;
    const int n = bid / (STRIPS * BB);

    if (tid < CIN) {
        constexpr float cinv = 1.f / (float)(BB * WIN * WIN);
        float ssum = 0.f, sq = 0.f;
        #pragma unroll
        for (int sh = 0; sh < NSH; ++sh) {
            ssum += aprev[sh * 2 * NN * CIN + n * CIN + tid];
            sq   += aprev[sh * 2 * NN * CIN + NN * CIN + n * CIN + tid];
        }
        float mu = ssum * cinv;
        float var = fmaxf(sq * cinv - mu * mu, 0.f);
        float rs = rsqrtf(var + 1e-5f);
        float w0 = hw[(n * 3 + 0) * CIN + tid];
        float w1 = hw[(n * 3 + 1) * CIN + tid];
        float w2 = hw[(n * 3 + 2) * CIN + tid];
        float c2 = w2 * 0.70710678118654752440f;
        float rs2 = rs * rs;
        cfA[tid] = (w0 - c2) - w1 * rs * mu + c2 * rs2 * mu * mu;
        cfB[tid] = w1 * rs - 2.f * c2 * rs2 * mu;
        cfC[tid] = c2 * rs2;
    }
    if (tid < 2 * COUT) ((float*)sred)[tid] = 0.f;
    __syncthreads();

    const int r0 = st * RB * STRIDE - 1;
    const bf16* abase = ain + (size_t)(n * BB + b) * (HIN * WIN * CIN);

    // halo columns (zero)
    {
        uint4 z4; z4.x = 0u; z4.y = 0u; z4.z = 0u; z4.w = 0u;
        for (int h = tid; h < IN_ROWS * 2 * CIN8; h += 256) {
            int c8 = h % CIN8;
            int t = h / CIN8;
            int xs = (t & 1) ? (XS - 1) : 0;
            int rr = t >> 1;
            int i16 = (rr * XS + xs) * CIN8 + (c8 ^ ((xs >> SW) & SM));
            *(uint4*)&tile[i16 * 8] = z4;
        }
    }
    // interior staging: global bf16 NHWC -> herpn -> LDS bf16 (swizzled)
    for (int h = tid; h < IN_ROWS * WIN * CIN8; h += 256) {
        int c8 = h % CIN8;
        int t = h / CIN8;
        int xx = t % WIN;
        int rr = t / WIN;
        int gr = r0 + rr;
        uint4 pk; pk.x = 0u; pk.y = 0u; pk.z = 0u; pk.w = 0u;
        if (gr >= 0 && gr < HIN) {
            uint4 raw = *(const uint4*)(abase + ((size_t)gr * WIN + xx) * CIN + c8 * 8);
            unsigned rw[4] = {raw.x, raw.y, raw.z, raw.w};
            unsigned ou[4];
            #pragma unroll
            for (int p = 0; p < 4; ++p) {
                int ci0 = c8 * 8 + p * 2;
                float v0 = bfbits2f(rw[p] & 0xffffu);
                float v1 = bfbits2f(rw[p] >> 16);
                v0 = fmaf(v0, fmaf(v0, cfC[ci0],     cfB[ci0]),     cfA[ci0]);
                v1 = fmaf(v1, fmaf(v1, cfC[ci0 + 1], cfB[ci0 + 1]), cfA[ci0 + 1]);
                ou[p] = (bbits(v1) << 16) | bbits(v0);
            }
            pk.x = ou[0]; pk.y = ou[1]; pk.z = ou[2]; pk.w = ou[3];
        }
        int xs = xx + 1;
        int i16 = (rr * XS + xs) * CIN8 + (c8 ^ ((xs >> SW) & SM));
        *(uint4*)&tile[i16 * 8] = pk;
    }
    __syncthreads();

    const int lane = tid & 63;
    const int wv = tid >> 6;
    const int qq = lane >> 4;      // quarter-wave (K-subgroup / D-row-group)
    const int ln = lane & 15;      // A: M index (pixel); B/D: N index (cout)

    int idxc[NK];
    #pragma unroll
    for (int c = 0; c < NK; ++c) {
        int tap, c8;
        if (CIN == 16)      { tap = 2 * c + (qq >> 1); c8 = qq & 1; if (tap > 8) tap = 0; }
        else if (CIN == 32) { tap = c;                 c8 = qq; }
        else                { tap = c >> 1;            c8 = ((c & 1) << 2) | qq; }
        int dy = tap / 3, dx = tap - dy * 3;
        int xs = ln * STRIDE + dx;
        idxc[c] = (dy * XS + xs) * CIN8 + (c8 ^ ((xs >> SW) & SM));
    }

    const bf16* wbase = wt + (size_t)n * (NK * 4 * COUT * 8);
    const bf16x8v zv = {0, 0, 0, 0, 0, 0, 0, 0};

    const int ntBeg = SPLITNT ? (int)blockIdx.y : 0;
    const int ntEnd = SPLITNT ? ntBeg + 1 : NT;
    for (int nt = ntBeg; nt < ntEnd; ++nt) {
        const int co0 = nt * 16;
        if constexpr (KCH == 0) {
            // ---- original path (stages 1-2): Bf[NK] resident, i outer ----
            bf16x8v Bf[NK];
            #pragma unroll
            for (int c = 0; c < NK; ++c)
                Bf[c] = *(const bf16x8v*)(wbase + ((size_t)(c * 4 + qq) * COUT + co0 + ln) * 8);
            float sA = 0.f, sQ = 0.f;
            for (int i = 0; i < MW; ++i) {
                const int mt = wv * MW + i;
                const int orow = mt / (WOUT / 16);
                const int x0 = (mt % (WOUT / 16)) * 16;
                const int moff = (orow * STRIDE * XS + x0 * STRIDE) * CIN8;
                f32x4v acc = {0.f, 0.f, 0.f, 0.f};
                #pragma unroll
                for (int c = 0; c < NK; ++c) {
                    bf16x8v av = *(const bf16x8v*)&tile[(idxc[c] + moff) * 8];
                    if (CIN == 16 && c == NK - 1) {
                        if (qq & 2) av = zv;           // K tail (k>=144) is zero
                    }
                    acc = __builtin_amdgcn_mfma_f32_16x16x32_bf16(av, Bf[c], acc, 0, 0, 0);
                }
                float s1 = acc[0] + acc[1] + acc[2] + acc[3];
                float q1 = fmaf(acc[0], acc[0], fmaf(acc[1], acc[1],
                           fmaf(acc[2], acc[2], acc[3] * acc[3])));
                s1 += __shfl_xor(s1, 16, 64); s1 += __shfl_xor(s1, 32, 64);
                q1 += __shfl_xor(q1, 16, 64); q1 += __shfl_xor(q1, 32, 64);
                sA += s1; sQ += q1;
                bf16* ob = aout + (((size_t)(n * BB + b) * HOUT + (st * RB + orow)) * WOUT + x0) * COUT
                           + co0 + ln;
                #pragma unroll
                for (int r = 0; r < 4; ++r)
                    ob[(qq * 4 + r) * COUT] = f2b(acc[r]);
            }
            if (qq == 0) {
                atomicAdd(&sred[0][co0 + ln], sA);
                atomicAdd(&sred[1][co0 + ln], sQ);
            }
        } else {
            // ---- chunked path (stages 3/4/5): Bf[KCH], kc outer, i inner.
            // Per-acc MFMA order still c=0..NK-1 ascending -> numerics identical.
            f32x4v accv[MW];
            int moff[MW];
            #pragma unroll
            for (int i = 0; i < MW; ++i) {
                const int mt = wv * MW + i;
                const int orow = mt / (WOUT / 16);
                const int x0 = (mt % (WOUT / 16)) * 16;
                moff[i] = (orow * STRIDE * XS + x0 * STRIDE) * CIN8;
                accv[i][0] = 0.f; accv[i][1] = 0.f; accv[i][2] = 0.f; accv[i][3] = 0.f;
            }
            #pragma unroll
            for (int kc = 0; kc < NK / KCH; ++kc) {
                bf16x8v Bf[KCH];
                #pragma unroll
                for (int c = 0; c < KCH; ++c)
                    Bf[c] = *(const bf16x8v*)(wbase +
                        ((size_t)((kc * KCH + c) * 4 + qq) * COUT + co0 + ln) * 8);
                #pragma unroll
                for (int i = 0; i < MW; ++i) {
                    #pragma unroll
                    for (int c = 0; c < KCH; ++c) {
                        bf16x8v av = *(const bf16x8v*)&tile[(idxc[kc * KCH + c] + moff[i]) * 8];
                        if (CIN == 16 && kc * KCH + c == NK - 1) {
                            if (qq & 2) av = zv;
                        }
                        accv[i] = __builtin_amdgcn_mfma_f32_16x16x32_bf16(av, Bf[c], accv[i], 0, 0, 0);
                    }
                }
            }
            float sA = 0.f, sQ = 0.f;
            #pragma unroll
            for (int i = 0; i < MW; ++i) {
                const int mt = wv * MW + i;
                const int orow = mt / (WOUT / 16);
                const int x0 = (mt % (WOUT / 16)) * 16;
                f32x4v acc = accv[i];
                float s1 = acc[0] + acc[1] + acc[2] + acc[3];
                float q1 = fmaf(acc[0], acc[0], fmaf(acc[1], acc[1],
                           fmaf(acc[2], acc[2], acc[3] * acc[3])));
                s1 += __shfl_xor(s1, 16, 64); s1 += __shfl_xor(s1, 32, 64);
                q1 += __shfl_xor(q1, 16, 64); q1 += __shfl_xor(q1, 32, 64);
                sA += s1; sQ += q1;
                bf16* ob = aout + (((size_t)(n * BB + b) * HOUT + (st * RB + orow)) * WOUT + x0) * COUT
                           + co0 + ln;
                #pragma unroll
                for (int r = 0; r < 4; ++r)
                    ob[(qq * 4 + r) * COUT] = f2b(acc[r]);
            }
            if (qq == 0) {
                atomicAdd(&sred[0][co0 + ln], sA);
                atomicAdd(&sred[1][co0 + ln], sQ);
            }
        }
    }
    __syncthreads();
    if constexpr (SPLITNT) {
        float* As = accum + (bid & (NSH - 1)) * (2 * NN * COUT);
        const int co0 = (int)blockIdx.y * 16;
        if (tid < 16) {
            atomicAdd(&As[n * COUT + co0 + tid], sred[0][co0 + tid]);
            atomicAdd(&As[NN * COUT + n * COUT + co0 + tid], sred[1][co0 + tid]);
        }
    } else {
        float* As = accum + (bid & (NSH - 1)) * (2 * NN * COUT);
        for (int t2 = tid; t2 < COUT; t2 += 256) {
            atomicAdd(&As[n * COUT + t2], sred[0][t2]);
            atomicAdd(&As[NN * COUT + n * COUT + t2], sred[1][t2]);
        }
    }
}

// ---------------------------------------------------------------------------
// pool: herpn(a5 NHWC bf16) -> quadrant means -> y[N,B,256] (fp32)
// ---------------------------------------------------------------------------
__launch_bounds__(256)
__global__ void pool_ker(const bf16* __restrict__ a5, const float* __restrict__ aprev,
                         const float* __restrict__ hw, float* __restrict__ y)
{
    const int n = blockIdx.x / BB, b = blockIdx.x % BB;
    const int f = threadIdx.x;
    const int c = f & 63, qd = f >> 6, qh = qd >> 1, qw = qd & 1;
    const bf16* p = a5 + (size_t)(n * BB + b) * 16384;
    const float cinv = 1.f / 8192.f;      // BB * 16 * 16
    float ssum0 = 0.f, sq0 = 0.f;
    #pragma unroll
    for (int sh = 0; sh < NSH; ++sh) {
        ssum0 += aprev[sh * 2 * NN * 64 + n * 64 + c];
        sq0   += aprev[sh * 2 * NN * 64 + NN * 64 + n * 64 + c];
    }
    float mu = ssum0 * cinv;
    float var = fmaxf(sq0 * cinv - mu * mu, 0.f);
    float rs = rsqrtf(var + 1e-5f);
    float w0 = hw[(n * 3 + 0) * 64 + c];
    float w1 = hw[(n * 3 + 1) * 64 + c];
    float w2 = hw[(n * 3 + 2) * 64 + c];
    float c2 = w2 * 0.70710678118654752440f;
    float rs2 = rs * rs;
    float A  = (w0 - c2) - w1 * rs * mu + c2 * rs2 * mu * mu;
    float Bc = w1 * rs - 2.f * c2 * rs2 * mu;
    float Cc = c2 * rs2;
    float ssum = 0.f;
    for (int iy = 0; iy < 8; ++iy)
        for (int ix = 0; ix < 8; ++ix) {
            float raw = b2f(p[(size_t)((qh * 8 + iy) * 16 + (qw * 8 + ix)) * 64 + c]);
            ssum += fmaf(raw, fmaf(raw, Cc, Bc), A);
        }
    y[(size_t)(n * BB + b) * 256 + c * 4 + qh * 2 + qw] = ssum * (1.f / 64.f);
}

// ---------------------------------------------------------------------------
// bn1: per (n,f) BN over B; writes batch-major yt[B][4096]
// ---------------------------------------------------------------------------
__launch_bounds__(256)
__global__ void bn1_ker(const float* __restrict__ y, const float* __restrict__ g,
                        const float* __restrict__ bta, float* __restrict__ yt)
{
    const int gid = blockIdx.x * 256 + threadIdx.x;   // n*256 + f
    const int n = gid >> 8;
    float s = 0.f, s2 = 0.f;
    for (int b = 0; b < BB; ++b) {
        float v = y[(size_t)((n * BB + b) * 256) + (gid & 255)];
        s += v;
        s2 = fmaf(v, v, s2);
    }
    float mu = s * (1.f / BB);
    float var = fmaxf(s2 * (1.f / BB) - mu * mu, 0.f);
    float rs = rsqrtf(var + 1e-5f);
    float gg = g[gid];
    float bb = bta[gid];
    for (int b = 0; b < BB; ++b) {
        float v = y[(size_t)((n * BB + b) * 256) + (gid & 255)];
        yt[(size_t)b * 4096 + gid] = fmaf((v - mu) * rs, gg, bb);
    }
}

// ---------------------------------------------------------------------------
// og head via MFMA split-K GEMM + fused og-BN + target write.
// ---------------------------------------------------------------------------
__launch_bounds__(256)
__global__ void og_mm_ker(const float* __restrict__ yt, const float* __restrict__ lin_w,
                          void* __restrict__ d_out, const int* __restrict__ flag)
{
    __shared__ float part[4][32][17];   // [wave][batch][col], +1 pad
    const int tid = threadIdx.x;
    const int wv = tid >> 6;            // K-shard of 1024
    const int lane = tid & 63;
    const int qq = lane >> 4;           // K-subgroup of 8 within a 32-chunk
    const int ln = lane & 15;
    const int j0 = blockIdx.x * 16;

    const float* wrow  = lin_w + (size_t)(j0 + ln) * 4096 + wv * 1024;
    const float* yrow0 = yt + (size_t)ln * 4096 + wv * 1024;
    const float* yrow1 = yt + (size_t)(16 + ln) * 4096 + wv * 1024;

    f32x4v acc0 = {0.f, 0.f, 0.f, 0.f}, acc1 = {0.f, 0.f, 0.f, 0.f};
    for (int kc = 0; kc < 32; ++kc) {
        const int ko = kc * 32 + qq * 8;
        bf16x8v Bf = pack8(*(const float4*)(wrow + ko), *(const float4*)(wrow + ko + 4));
        bf16x8v A0 = pack8(*(const float4*)(yrow0 + ko), *(const float4*)(yrow0 + ko + 4));
        bf16x8v A1 = pack8(*(const float4*)(yrow1 + ko), *(const float4*)(yrow1 + ko + 4));
        acc0 = __builtin_amdgcn_mfma_f32_16x16x32_bf16(A0, Bf, acc0, 0, 0, 0);
        acc1 = __builtin_amdgcn_mfma_f32_16x16x32_bf16(A1, Bf, acc1, 0, 0, 0);
    }
    #pragma unroll
    for (int r = 0; r < 4; ++r) {
        part[wv][qq * 4 + r][ln]      = acc0[r];
        part[wv][16 + qq * 4 + r][ln] = acc1[r];
    }
    __syncthreads();

    if (tid < 16) {
        float vsum = 0.f, vsq = 0.f;
        for (int b = 0; b < BB; ++b) {
            float v = part[0][b][tid] + part[1][b][tid] + part[2][b][tid] + part[3][b][tid];
            vsum += v; vsq = fmaf(v, v, vsq);
        }
        float mu = vsum * (1.f / BB);
        float var = fmaxf(vsq * (1.f / BB) - mu * mu, 0.f);
        float rs = rsqrtf(var + 1e-5f);
        const int j = j0 + tid;
        const bool isf32 = (*flag != 0);
        for (int b = 0; b < BB; ++b) {
            float v = part[0][b][tid] + part[1][b][tid] + part[2][b][tid] + part[3][b][tid];
            float o = (v - mu) * rs;
            if (isf32) ((float*)d_out)[b * 256 + j] = o;
            else       ((bf16*)d_out)[b * 256 + j] = f2b(o);
        }
        float t = (float)(j & 15);
        if (isf32) { ((float*)d_out)[16384 + j] = t; ((float*)d_out)[16640 + j] = t; }
        else       { ((bf16*)d_out)[16384 + j] = f2b(t); ((bf16*)d_out)[16640 + j] = f2b(t); }
    }
}

// ---------------------------------------------------------------------------
// pred head
// ---------------------------------------------------------------------------
__launch_bounds__(256)
__global__ void pred_ker(const float* __restrict__ yt, const float* __restrict__ jig_w,
                         const float* __restrict__ jig_b, void* __restrict__ d_out,
                         const int* __restrict__ flag)
{
    __shared__ float sy[256];
    const int b = blockIdx.x >> 4, n = blockIdx.x & 15;
    sy[threadIdx.x] = yt[(size_t)b * 4096 + n * 256 + threadIdx.x];
    __syncthreads();
    const int k = threadIdx.x >> 4, part = threadIdx.x & 15;
    const float* wrow = jig_w + k * 256 + part * 16;
    const float* srow = sy + part * 16;
    float p = 0.f;
    #pragma unroll
    for (int t = 0; t < 16; ++t) p = fmaf(srow[t], wrow[t], p);
    #pragma unroll
    for (int off = 8; off > 0; off >>= 1) p += __shfl_down(p, off, 16);
    if (part == 0) {
        float v = p + jig_b[k];
        int pidx = 8192 + (b * 16 + n) * 16 + k;
        if (*flag) ((float*)d_out)[pidx] = v;
        else       ((bf16*)d_out)[pidx] = f2b(v);
    }
}

// ---------------------------------------------------------------------------
extern "C" void kernel_launch(void* const* d_in, const int* in_sizes, int n_in,
                              void* d_out, int out_size, void* d_ws, size_t ws_size,
                              hipStream_t stream)
{
    char* wsb = (char*)d_ws;
    int*   flag   = (int*)wsb;                      // @0
    float* y      = (float*)(wsb + 131072);         // 131072 f
    float* yt     = (float*)(wsb + 655360);         // 131072 f  [B][4096]
    bf16*  wtb    = (bf16*)(wsb + 1310720);         // packed bf16 MFMA weights (2.33MB)
    float* accumZ = (float*)(wsb + 3670016);        // sharded stats: 114688 f = 448KB
    float* staged = (float*)(wsb + 6029312);        // f32 arena

    // sharded accumulators: per stage NSH shards x [2][NN*C]
    float* A0 = accumZ + 0;       // C=16: 16*2*256 = 8192 f
    float* A1 = accumZ + 8192;    // C=16: 8192 f
    float* A2 = accumZ + 16384;   // C=32: 16384 f
    float* A3 = accumZ + 32768;   // C=32: 16384 f
    float* A4 = accumZ + 49152;   // C=64: 32768 f
    float* A5 = accumZ + 81920;   // C=64: 32768 f  (end 114688 f)

    bf16* wt1b = wtb;                    // 16*5*4*16*8  = 40960
    bf16* wt2b = wt1b + 40960;           // 16*5*4*32*8  = 81920
    bf16* wt3b = wt2b + 81920;           // 16*9*4*32*8  = 147456
    bf16* wt4b = wt3b + 147456;          // 16*9*4*64*8  = 294912
    bf16* wt5b = wt4b + 294912;          // 16*18*4*64*8 = 589824

    CvtArgs ca;
    int off = 0, maxc = 0;
    for (int i = 0; i < 19; ++i) {
        ca.src[i] = d_in[i];
        ca.cnt[i] = in_sizes[i];
        ca.off[i] = off;
        off += in_sizes[i];
        if (in_sizes[i] > maxc) maxc = in_sizes[i];
    }
    float* sx      = staged + ca.off[0];
    float* scw0    = staged + ca.off[1];
    float* shw1    = staged + ca.off[2];
    float* scw1    = staged + ca.off[3];
    float* shw2    = staged + ca.off[4];
    float* scw2    = staged + ca.off[5];
    float* shw3    = staged + ca.off[6];
    float* scw3    = staged + ca.off[7];
    float* shw4    = staged + ca.off[8];
    float* scw4    = staged + ca.off[9];
    float* shw5    = staged + ca.off[10];
    float* scw5    = staged + ca.off[11];
    float* spool   = staged + ca.off[12];
    float* sg      = staged + ca.off[13];
    float* sb      = staged + ca.off[14];
    float* slin_w  = staged + ca.off[15];
    float* slin_b  = staged + ca.off[16];
    float* sjig_w  = staged + ca.off[17];
    float* sjig_b  = staged + ca.off[18];
    (void)slin_b;  // BN-invariant, unused

    size_t stagedEnd = 6029312ull + (size_t)off * 4ull;
    size_t r1off = (stagedEnd + (1ull << 20)) & ~((1ull << 20) - 1ull);

    hipMemsetAsync(flag, 0, 4, stream);
    detect_ker<<<32, 256, 0, stream>>>((const uint4*)d_in[0], flag);
    convert_ker<<<dim3((maxc + 2047) / 2048, 19), 256, 0, stream>>>(ca, staged, flag);

    WpArgs wp;
    wp.src[0] = scw1; wp.dst[0] = wt1b; wp.cout[0] = 16; wp.cin[0] = 16; wp.nk[0] = 5;  wp.tot[0] = 16*5*4*16*8;
    wp.src[1] = scw2; wp.dst[1] = wt2b; wp.cout[1] = 32; wp.cin[1] = 16; wp.nk[1] = 5;  wp.tot[1] = 16*5*4*32*8;
    wp.src[2] = scw3; wp.dst[2] = wt3b; wp.cout[2] = 32; wp.cin[2] = 32; wp.nk[2] = 9;  wp.tot[2] = 16*9*4*32*8;
    wp.src[3] = scw4; wp.dst[3] = wt4b; wp.cout[3] = 64; wp.cin[3] = 32; wp.nk[3] = 9;  wp.tot[3] = 16*9*4*64*8;
    wp.src[4] = scw5; wp.dst[4] = wt5b; wp.cout[4] = 64; wp.cin[4] = 64; wp.nk[4] = 18; wp.tot[4] = 16*18*4*64*8;
    wprep_ker<<<dim3(2304, 5), 256, 0, stream>>>(wp);

    hipMemsetAsync(accumZ, 0, 114688 * sizeof(float), stream);

    // activation ping-pong: two 64 MiB regions (all activations bf16 NHWC)
    char* rA = wsb + r1off;
    char* rB = wsb + r1off + (64ull << 20);
    bf16* a0 = (bf16*)rB;
    bf16* a1 = (bf16*)rA;
    bf16* a2 = (bf16*)rB;
    bf16* a3 = (bf16*)rA;
    bf16* a4 = (bf16*)rB;
    bf16* a5 = (bf16*)rA;

    conv0w_ker<<<NN * BB * 8, 256, 0, stream>>>(sx, scw0, a0, A0);
    mconv_ker<16, 16, 64, 1, 8, 0, 1, false><<<NN * BB * 8, 256, 0, stream>>>(a0, A0, shw1, wt1b, a1, A1);
    mconv_ker<16, 32, 64, 2, 8, 0, 1, false><<<NN * BB * 4, 256, 0, stream>>>(a1, A1, shw2, wt2b, a2, A2);
    mconv_ker<32, 32, 32, 1, 8, 3, 3, true><<<dim3(NN * BB * 4, 2), 256, 0, stream>>>(a2, A2, shw3, wt3b, a3, A3);
    mconv_ker<32, 64, 32, 2, 8, 3, 3, true><<<dim3(NN * BB * 2, 4), 256, 0, stream>>>(a3, A3, shw4, wt4b, a4, A4);
    mconv_ker<64, 64, 16, 1, 16, 6, 3, true><<<dim3(NN * BB, 4), 256, 0, stream>>>(a4, A4, shw5, wt5b, a5, A5);
    pool_ker<<<NN * BB, 256, 0, stream>>>(a5, A5, spool, y);

    bn1_ker<<<NN, 256, 0, stream>>>(y, sg, sb, yt);
    og_mm_ker<<<16, 256, 0, stream>>>(yt, slin_w, d_out, flag);
    pred_ker<<<BB * NN, 256, 0, stream>>>(yt, sjig_w, sjig_b, d_out, flag);
}

// Round 14
// 336.810 us; speedup vs baseline: 1.1315x; 1.1315x over previous
//
#include <hip/hip_runtime.h>
#include <hip/hip_bf16.h>

typedef __hip_bfloat16 bf16;

#define BB 32   // batch
#define NN 16   // patches / backbones
#define NSH 16  // stats-accumulator shards (atomic contention /16)

using bf16x8v = __attribute__((ext_vector_type(8))) short;  // 8 bf16 (4 VGPRs)
using f32x4v  = __attribute__((ext_vector_type(4))) float;  // 4 fp32

__device__ __forceinline__ float b2f(bf16 v){ return __bfloat162float(v); }
__device__ __forceinline__ bf16  f2b(float v){ return __float2bfloat16(v); }
__device__ __forceinline__ float bfbits2f(unsigned int h){
    unsigned int x = h << 16; float f; __builtin_memcpy(&f, &x, 4); return f;
}
__device__ __forceinline__ unsigned bbits(float f){
    bf16 h = f2b(f); unsigned short u; __builtin_memcpy(&u, &h, 2); return (unsigned)u;
}
__device__ __forceinline__ bf16x8v pack8(float4 a, float4 b){
    bf16x8v r;
    r[0] = (short)bbits(a.x); r[1] = (short)bbits(a.y);
    r[2] = (short)bbits(a.z); r[3] = (short)bbits(a.w);
    r[4] = (short)bbits(b.x); r[5] = (short)bbits(b.y);
    r[6] = (short)bbits(b.z); r[7] = (short)bbits(b.w);
    return r;
}

// ---------------------------------------------------------------------------
// dtype probe: flag=1 -> float32 inputs; 0 -> bf16. (32 blocks, uint4 loads)
// ---------------------------------------------------------------------------
__launch_bounds__(256)
__global__ void detect_ker(const uint4* __restrict__ xs, int* __restrict__ flag)
{
    const int base = blockIdx.x * 1024 + threadIdx.x;
    int cnt = 0;
    #pragma unroll
    for (int k = 0; k < 4; ++k) {
        uint4 v = xs[base + k * 256];
        unsigned w[4] = {v.x, v.y, v.z, v.w};
        #pragma unroll
        for (int p = 0; p < 4; ++p) {
            if ((w[p] & 0x7F80u) == 0x7F80u) cnt++;
            if (((w[p] >> 16) & 0x7F80u) == 0x7F80u) cnt++;
        }
    }
    unsigned long long m = __ballot(cnt != 0);
    if ((threadIdx.x & 63) == 0 && m != 0ull) atomicOr(flag, 1);
}

// ---------------------------------------------------------------------------
// stage all inputs into a contiguous FLOAT arena
// ---------------------------------------------------------------------------
struct CvtArgs { const void* src[19]; int cnt[19]; int off[19]; };

__launch_bounds__(256)
__global__ void convert_ker(CvtArgs a, float* __restrict__ dst, const int* __restrict__ flag)
{
    const int which = blockIdx.y;
    const int cnt = a.cnt[which];
    if ((int)blockIdx.x * 2048 >= cnt) return;
    const int base = blockIdx.x * 2048 + threadIdx.x;
    float* d = dst + a.off[which];
    if (*flag) {
        const float* s = (const float*)a.src[which];
        #pragma unroll
        for (int k = 0; k < 8; ++k) { int j = base + k * 256; if (j < cnt) d[j] = s[j]; }
    } else {
        const bf16* s = (const bf16*)a.src[which];
        #pragma unroll
        for (int k = 0; k < 8; ++k) { int j = base + k * 256; if (j < cnt) d[j] = b2f(s[j]); }
    }
}

// ---------------------------------------------------------------------------
// weight prep for MFMA convs: f32 [n][co][ci][3][3] -> bf16 B-fragment layout
// ---------------------------------------------------------------------------
struct WpArgs { const float* src[5]; bf16* dst[5]; int cout[5]; int cin[5]; int nk[5]; int tot[5]; };

__launch_bounds__(256)
__global__ void wprep_ker(WpArgs a)
{
    const int stg = blockIdx.y;
    const int cout = a.cout[stg], cin = a.cin[stg], nk = a.nk[stg];
    int idx = blockIdx.x * 256 + threadIdx.x;
    if (idx >= a.tot[stg]) return;
    int j  = idx & 7;
    int co = (idx >> 3) % cout;
    int rest = (idx >> 3) / cout;      // = (n*nk + c)*4 + k8
    int k8 = rest & 3;
    int cn = rest >> 2;                // n*nk + c
    int c  = cn % nk;
    int n  = cn / nk;
    int k  = c * 32 + k8 * 8 + j;
    int tap = k / cin;
    int ci  = k - tap * cin;
    float v = 0.f;
    if (tap < 9) v = a.src[stg][((size_t)(n * cout + co) * cin + ci) * 9 + tap];
    a.dst[stg][idx] = f2b(v);
}

// ---------------------------------------------------------------------------
// conv0 (VERIFIED VALU path): x -> a0 NHWC bf16 + sharded stats atomics.
// conv0 arithmetic is FROZEN (absmax 0.2969 vs 0.30; R8/R9 showed any
// numerics change crosses the boundary). XCD-chunked block swizzle only.
// ---------------------------------------------------------------------------
__launch_bounds__(256)
__global__ void conv0w_ker(const float* __restrict__ x, const float* __restrict__ w,
                           bf16* __restrict__ a0, float* __restrict__ accum)
{
    constexpr int STRIP = 8, STRIPS = 8, IN_ROWS = 10, TW = 66;
    constexpr int G = NN * BB * STRIPS;
    __shared__ float tile[3][IN_ROWS][TW];    // 7920 B
    const int tid = threadIdx.x;
    const int bid = (blockIdx.x & 7) * (G >> 3) + (blockIdx.x >> 3);  // XCD-chunked
    const int st = bid % STRIPS;
    const int b = (bid / STRIPS) % BB;
    const int n = bid / (STRIPS * BB);
    const int pr = (n >> 2) * 64, pc = (n & 3) * 64;
    const int r0 = st * STRIP - 1;

    for (int idx = tid; idx < 3 * IN_ROWS * TW; idx += 256) {
        int ci = idx / (IN_ROWS * TW);
        int rem = idx - ci * (IN_ROWS * TW);
        int rr = rem / TW, cc = rem - rr * TW;
        int gr = r0 + rr, gc = cc - 1;
        float v = 0.f;
        if (gr >= 0 && gr < 64 && gc >= 0 && gc < 64)
            v = x[((size_t)(b * 3 + ci) * 256 + (pr + gr)) * 256 + (pc + gc)];
        tile[ci][rr][cc] = v;
    }
    __syncthreads();

    const int xo = tid & 63;
    const int wv = tid >> 6;
    const int co0 = wv * 4;
    const float* wb = w + __builtin_amdgcn_readfirstlane((n * 16 + co0) * 27);

    float acc[4][STRIP];
    #pragma unroll
    for (int t = 0; t < 4; ++t)
        #pragma unroll
        for (int r = 0; r < STRIP; ++r) acc[t][r] = 0.f;

    #pragma unroll
    for (int ci = 0; ci < 3; ++ci) {
        float wr[4][9];
        #pragma unroll
        for (int t = 0; t < 4; ++t)
            #pragma unroll
            for (int j = 0; j < 9; ++j)
                wr[t][j] = wb[t * 27 + ci * 9 + j];
        float win[3][3];
        #pragma unroll
        for (int c0 = 0; c0 < 3; ++c0) {
            win[0][c0] = tile[ci][0][xo + c0];
            win[1][c0] = tile[ci][1][xo + c0];
        }
        #pragma unroll
        for (int ry = 0; ry < STRIP; ++ry) {
            #pragma unroll
            for (int c0 = 0; c0 < 3; ++c0)
                win[(ry + 2) % 3][c0] = tile[ci][ry + 2][xo + c0];
            #pragma unroll
            for (int ky = 0; ky < 3; ++ky)
                #pragma unroll
                for (int kx = 0; kx < 3; ++kx) {
                    float v = win[(ry + ky) % 3][kx];
                    #pragma unroll
                    for (int t = 0; t < 4; ++t)
                        acc[t][ry] = fmaf(v, wr[t][ky * 3 + kx], acc[t][ry]);
                }
        }
    }

    // direct NHWC packed store: 4 couts = 8B per (pixel, wave)
    bf16* ab = a0 + (size_t)(n * BB + b) * 65536 + (size_t)st * 8192;
    #pragma unroll
    for (int r = 0; r < STRIP; ++r) {
        uint2 pk;
        pk.x = (bbits(acc[1][r]) << 16) | bbits(acc[0][r]);
        pk.y = (bbits(acc[3][r]) << 16) | bbits(acc[2][r]);
        *(uint2*)&ab[(size_t)(r * 64 + xo) * 16 + co0] = pk;
    }

    // stats
    float s[4], q[4];
    #pragma unroll
    for (int t = 0; t < 4; ++t) {
        s[t] = 0.f; q[t] = 0.f;
        #pragma unroll
        for (int r = 0; r < STRIP; ++r) {
            s[t] += acc[t][r];
            q[t] = fmaf(acc[t][r], acc[t][r], q[t]);
        }
    }
    #pragma unroll
    for (int off = 32; off > 0; off >>= 1) {
        #pragma unroll
        for (int t = 0; t < 4; ++t) {
            s[t] += __shfl_down(s[t], off, 64);
            q[t] += __shfl_down(q[t], off, 64);
        }
    }
    if (xo == 0) {
        float* As = accum + (bid & (NSH - 1)) * (2 * NN * 16);
        #pragma unroll
        for (int t = 0; t < 4; ++t) {
            atomicAdd(&As[n * 16 + co0 + t],           s[t]);
            atomicAdd(&As[256 + n * 16 + co0 + t], q[t]);
        }
    }
}

// ---------------------------------------------------------------------------
// fused herpn + 3x3 conv via MFMA implicit GEMM (NHWC bf16 activations).
// R14: post-mortem of R13 (+43us regression) — SPLITNT multiplies staging
// work and only pays when occupancy is hard-capped (stage 5: 512 blocks,
// VGPR 176, 43KB LDS). Stages 3/4 revert to single-grid (staging once) but
// KEEP KCH=3 + MINW=3 (VGPR relief, no cost term, numerics identical).
// ---------------------------------------------------------------------------
template<int CIN, int COUT, int WIN, int STRIDE, int RB, int KCH, int MINW, bool SPLITNT>
__launch_bounds__(256, MINW)
__global__ void mconv_ker(const bf16* __restrict__ ain, const float* __restrict__ aprev,
                          const float* __restrict__ hw, const bf16* __restrict__ wt,
                          bf16* __restrict__ aout, float* __restrict__ accum)
{
    constexpr int HIN = WIN;
    constexpr int WOUT = WIN / STRIDE, HOUT = WIN / STRIDE;
    constexpr int CIN8 = CIN / 8;                 // 16B chunks per pixel
    constexpr int XS = WIN + 2;                   // x slots incl halo cols
    constexpr int IN_ROWS = STRIDE * (RB - 1) + 3;
    constexpr int STRIPS = HOUT / RB;
    constexpr int G = NN * BB * STRIPS;           // x-grid size (divisible by 8)
    constexpr int NK = (CIN == 16) ? 5 : (9 * CIN) / 32;   // K chunks of 32
    constexpr int NT = COUT / 16;                 // N tiles
    constexpr int MT = RB * (WOUT / 16);          // M tiles per block
    constexpr int MW = MT / 4;                    // M tiles per wave
    constexpr int SW = (CIN8 == 2) ? 2 : ((CIN8 == 4) ? 1 : 0);
    constexpr int SM = CIN8 - 1;
    static_assert(MT % 4 == 0, "4 waves");
    static_assert(G % 8 == 0, "bijective XCD swizzle");
    static_assert(KCH == 0 || NK % KCH == 0, "K chunking divides NK");

    __shared__ __align__(16) short tile[IN_ROWS * XS * CIN8 * 8];
    __shared__ float cfA[CIN], cfB[CIN], cfC[CIN];
    __shared__ float sred[2][COUT];

    const int tid = threadIdx.x;
    const int bid = (blockIdx.x & 7) * (G >> 3) + (blockIdx.x >> 3);  // XCD-chunked
    const int st = bid % STRIPS;
    const int b = (bid / STRIPS) % BB;
    const int n = bid / (STRIPS * BB);

    if (tid < CIN) {
        constexpr float cinv = 1.f / (float)(BB * WIN * WIN);
        float ssum = 0.f, sq = 0.f;
        #pragma unroll
        for (int sh = 0; sh < NSH; ++sh) {
            ssum += aprev[sh * 2 * NN * CIN + n * CIN + tid];
            sq   += aprev[sh * 2 * NN * CIN + NN * CIN + n * CIN + tid];
        }
        float mu = ssum * cinv;
        float var = fmaxf(sq * cinv - mu * mu, 0.f);
        float rs = rsqrtf(var + 1e-5f);
        float w0 = hw[(n * 3 + 0) * CIN + tid];
        float w1 = hw[(n * 3 + 1) * CIN + tid];
        float w2 = hw[(n * 3 + 2) * CIN + tid];
        float c2 = w2 * 0.70710678118654752440f;
        float rs2 = rs * rs;
        cfA[tid] = (w0 - c2) - w1 * rs * mu + c2 * rs2 * mu * mu;
        cfB[tid] = w1 * rs - 2.f * c2 * rs2 * mu;
        cfC[tid] = c2 * rs2;
    }
    if (tid < 2 * COUT) ((float*)sred)[tid] = 0.f;
    __syncthreads();

    const int r0 = st * RB * STRIDE - 1;
    const bf16* abase = ain + (size_t)(n * BB + b) * (HIN * WIN * CIN);

    // halo columns (zero)
    {
        uint4 z4; z4.x = 0u; z4.y = 0u; z4.z = 0u; z4.w = 0u;
        for (int h = tid; h < IN_ROWS * 2 * CIN8; h += 256) {
            int c8 = h % CIN8;
            int t = h / CIN8;
            int xs = (t & 1) ? (XS - 1) : 0;
            int rr = t >> 1;
            int i16 = (rr * XS + xs) * CIN8 + (c8 ^ ((xs >> SW) & SM));
            *(uint4*)&tile[i16 * 8] = z4;
        }
    }
    // interior staging: global bf16 NHWC -> herpn -> LDS bf16 (swizzled)
    for (int h = tid; h < IN_ROWS * WIN * CIN8; h += 256) {
        int c8 = h % CIN8;
        int t = h / CIN8;
        int xx = t % WIN;
        int rr = t / WIN;
        int gr = r0 + rr;
        uint4 pk; pk.x = 0u; pk.y = 0u; pk.z = 0u; pk.w = 0u;
        if (gr >= 0 && gr < HIN) {
            uint4 raw = *(const uint4*)(abase + ((size_t)gr * WIN + xx) * CIN + c8 * 8);
            unsigned rw[4] = {raw.x, raw.y, raw.z, raw.w};
            unsigned ou[4];
            #pragma unroll
            for (int p = 0; p < 4; ++p) {
                int ci0 = c8 * 8 + p * 2;
                float v0 = bfbits2f(rw[p] & 0xffffu);
                float v1 = bfbits2f(rw[p] >> 16);
                v0 = fmaf(v0, fmaf(v0, cfC[ci0],     cfB[ci0]),     cfA[ci0]);
                v1 = fmaf(v1, fmaf(v1, cfC[ci0 + 1], cfB[ci0 + 1]), cfA[ci0 + 1]);
                ou[p] = (bbits(v1) << 16) | bbits(v0);
            }
            pk.x = ou[0]; pk.y = ou[1]; pk.z = ou[2]; pk.w = ou[3];
        }
        int xs = xx + 1;
        int i16 = (rr * XS + xs) * CIN8 + (c8 ^ ((xs >> SW) & SM));
        *(uint4*)&tile[i16 * 8] = pk;
    }
    __syncthreads();

    const int lane = tid & 63;
    const int wv = tid >> 6;
    const int qq = lane >> 4;      // quarter-wave (K-subgroup / D-row-group)
    const int ln = lane & 15;      // A: M index (pixel); B/D: N index (cout)

    int idxc[NK];
    #pragma unroll
    for (int c = 0; c < NK; ++c) {
        int tap, c8;
        if (CIN == 16)      { tap = 2 * c + (qq >> 1); c8 = qq & 1; if (tap > 8) tap = 0; }
        else if (CIN == 32) { tap = c;                 c8 = qq; }
        else                { tap = c >> 1;            c8 = ((c & 1) << 2) | qq; }
        int dy = tap / 3, dx = tap - dy * 3;
        int xs = ln * STRIDE + dx;
        idxc[c] = (dy * XS + xs) * CIN8 + (c8 ^ ((xs >> SW) & SM));
    }

    const bf16* wbase = wt + (size_t)n * (NK * 4 * COUT * 8);
    const bf16x8v zv = {0, 0, 0, 0, 0, 0, 0, 0};

    const int ntBeg = SPLITNT ? (int)blockIdx.y : 0;
    const int ntEnd = SPLITNT ? ntBeg + 1 : NT;
    for (int nt = ntBeg; nt < ntEnd; ++nt) {
        const int co0 = nt * 16;
        if constexpr (KCH == 0) {
            // ---- original path (stages 1-2): Bf[NK] resident, i outer ----
            bf16x8v Bf[NK];
            #pragma unroll
            for (int c = 0; c < NK; ++c)
                Bf[c] = *(const bf16x8v*)(wbase + ((size_t)(c * 4 + qq) * COUT + co0 + ln) * 8);
            float sA = 0.f, sQ = 0.f;
            for (int i = 0; i < MW; ++i) {
                const int mt = wv * MW + i;
                const int orow = mt / (WOUT / 16);
                const int x0 = (mt % (WOUT / 16)) * 16;
                const int moff = (orow * STRIDE * XS + x0 * STRIDE) * CIN8;
                f32x4v acc = {0.f, 0.f, 0.f, 0.f};
                #pragma unroll
                for (int c = 0; c < NK; ++c) {
                    bf16x8v av = *(const bf16x8v*)&tile[(idxc[c] + moff) * 8];
                    if (CIN == 16 && c == NK - 1) {
                        if (qq & 2) av = zv;           // K tail (k>=144) is zero
                    }
                    acc = __builtin_amdgcn_mfma_f32_16x16x32_bf16(av, Bf[c], acc, 0, 0, 0);
                }
                float s1 = acc[0] + acc[1] + acc[2] + acc[3];
                float q1 = fmaf(acc[0], acc[0], fmaf(acc[1], acc[1],
                           fmaf(acc[2], acc[2], acc[3] * acc[3])));
                s1 += __shfl_xor(s1, 16, 64); s1 += __shfl_xor(s1, 32, 64);
                q1 += __shfl_xor(q1, 16, 64); q1 += __shfl_xor(q1, 32, 64);
                sA += s1; sQ += q1;
                bf16* ob = aout + (((size_t)(n * BB + b) * HOUT + (st * RB + orow)) * WOUT + x0) * COUT
                           + co0 + ln;
                #pragma unroll
                for (int r = 0; r < 4; ++r)
                    ob[(qq * 4 + r) * COUT] = f2b(acc[r]);
            }
            if (qq == 0) {
                atomicAdd(&sred[0][co0 + ln], sA);
                atomicAdd(&sred[1][co0 + ln], sQ);
            }
        } else {
            // ---- chunked path (stages 3/4/5): Bf[KCH], kc outer, i inner.
            // Per-acc MFMA order still c=0..NK-1 ascending -> numerics identical.
            f32x4v accv[MW];
            int moff[MW];
            #pragma unroll
            for (int i = 0; i < MW; ++i) {
                const int mt = wv * MW + i;
                const int orow = mt / (WOUT / 16);
                const int x0 = (mt % (WOUT / 16)) * 16;
                moff[i] = (orow * STRIDE * XS + x0 * STRIDE) * CIN8;
                accv[i][0] = 0.f; accv[i][1] = 0.f; accv[i][2] = 0.f; accv[i][3] = 0.f;
            }
            #pragma unroll
            for (int kc = 0; kc < NK / KCH; ++kc) {
                bf16x8v Bf[KCH];
                #pragma unroll
                for (int c = 0; c < KCH; ++c)
                    Bf[c] = *(const bf16x8v*)(wbase +
                        ((size_t)((kc * KCH + c) * 4 + qq) * COUT + co0 + ln) * 8);
                #pragma unroll
                for (int i = 0; i < MW; ++i) {
                    #pragma unroll
                    for (int c = 0; c < KCH; ++c) {
                        bf16x8v av = *(const bf16x8v*)&tile[(idxc[kc * KCH + c] + moff[i]) * 8];
                        if (CIN == 16 && kc * KCH + c == NK - 1) {
                            if (qq & 2) av = zv;
                        }
                        accv[i] = __builtin_amdgcn_mfma_f32_16x16x32_bf16(av, Bf[c], accv[i], 0, 0, 0);
                    }
                }
            }
            float sA = 0.f, sQ = 0.f;
            #pragma unroll
            for (int i = 0; i < MW; ++i) {
                const int mt = wv * MW + i;
                const int orow = mt / (WOUT / 16);
                const int x0 = (mt % (WOUT / 16)) * 16;
                f32x4v acc = accv[i];
                float s1 = acc[0] + acc[1] + acc[2] + acc[3];
                float q1 = fmaf(acc[0], acc[0], fmaf(acc[1], acc[1],
                           fmaf(acc[2], acc[2], acc[3] * acc[3])));
                s1 += __shfl_xor(s1, 16, 64); s1 += __shfl_xor(s1, 32, 64);
                q1 += __shfl_xor(q1, 16, 64); q1 += __shfl_xor(q1, 32, 64);
                sA += s1; sQ += q1;
                bf16* ob = aout + (((size_t)(n * BB + b) * HOUT + (st * RB + orow)) * WOUT + x0) * COUT
                           + co0 + ln;
                #pragma unroll
                for (int r = 0; r < 4; ++r)
                    ob[(qq * 4 + r) * COUT] = f2b(acc[r]);
            }
            if (qq == 0) {
                atomicAdd(&sred[0][co0 + ln], sA);
                atomicAdd(&sred[1][co0 + ln], sQ);
            }
        }
    }
    __syncthreads();
    if constexpr (SPLITNT) {
        float* As = accum + (bid & (NSH - 1)) * (2 * NN * COUT);
        const int co0 = (int)blockIdx.y * 16;
        if (tid < 16) {
            atomicAdd(&As[n * COUT + co0 + tid], sred[0][co0 + tid]);
            atomicAdd(&As[NN * COUT + n * COUT + co0 + tid], sred[1][co0 + tid]);
        }
    } else {
        float* As = accum + (bid & (NSH - 1)) * (2 * NN * COUT);
        for (int t2 = tid; t2 < COUT; t2 += 256) {
            atomicAdd(&As[n * COUT + t2], sred[0][t2]);
            atomicAdd(&As[NN * COUT + n * COUT + t2], sred[1][t2]);
        }
    }
}

// ---------------------------------------------------------------------------
// pool: herpn(a5 NHWC bf16) -> quadrant means -> y[N,B,256] (fp32)
// ---------------------------------------------------------------------------
__launch_bounds__(256)
__global__ void pool_ker(const bf16* __restrict__ a5, const float* __restrict__ aprev,
                         const float* __restrict__ hw, float* __restrict__ y)
{
    const int n = blockIdx.x / BB, b = blockIdx.x % BB;
    const int f = threadIdx.x;
    const int c = f & 63, qd = f >> 6, qh = qd >> 1, qw = qd & 1;
    const bf16* p = a5 + (size_t)(n * BB + b) * 16384;
    const float cinv = 1.f / 8192.f;      // BB * 16 * 16
    float ssum0 = 0.f, sq0 = 0.f;
    #pragma unroll
    for (int sh = 0; sh < NSH; ++sh) {
        ssum0 += aprev[sh * 2 * NN * 64 + n * 64 + c];
        sq0   += aprev[sh * 2 * NN * 64 + NN * 64 + n * 64 + c];
    }
    float mu = ssum0 * cinv;
    float var = fmaxf(sq0 * cinv - mu * mu, 0.f);
    float rs = rsqrtf(var + 1e-5f);
    float w0 = hw[(n * 3 + 0) * 64 + c];
    float w1 = hw[(n * 3 + 1) * 64 + c];
    float w2 = hw[(n * 3 + 2) * 64 + c];
    float c2 = w2 * 0.70710678118654752440f;
    float rs2 = rs * rs;
    float A  = (w0 - c2) - w1 * rs * mu + c2 * rs2 * mu * mu;
    float Bc = w1 * rs - 2.f * c2 * rs2 * mu;
    float Cc = c2 * rs2;
    float ssum = 0.f;
    for (int iy = 0; iy < 8; ++iy)
        for (int ix = 0; ix < 8; ++ix) {
            float raw = b2f(p[(size_t)((qh * 8 + iy) * 16 + (qw * 8 + ix)) * 64 + c]);
            ssum += fmaf(raw, fmaf(raw, Cc, Bc), A);
        }
    y[(size_t)(n * BB + b) * 256 + c * 4 + qh * 2 + qw] = ssum * (1.f / 64.f);
}

// ---------------------------------------------------------------------------
// bn1: per (n,f) BN over B; writes batch-major yt[B][4096]
// ---------------------------------------------------------------------------
__launch_bounds__(256)
__global__ void bn1_ker(const float* __restrict__ y, const float* __restrict__ g,
                        const float* __restrict__ bta, float* __restrict__ yt)
{
    const int gid = blockIdx.x * 256 + threadIdx.x;   // n*256 + f
    const int n = gid >> 8;
    float s = 0.f, s2 = 0.f;
    for (int b = 0; b < BB; ++b) {
        float v = y[(size_t)((n * BB + b) * 256) + (gid & 255)];
        s += v;
        s2 = fmaf(v, v, s2);
    }
    float mu = s * (1.f / BB);
    float var = fmaxf(s2 * (1.f / BB) - mu * mu, 0.f);
    float rs = rsqrtf(var + 1e-5f);
    float gg = g[gid];
    float bb = bta[gid];
    for (int b = 0; b < BB; ++b) {
        float v = y[(size_t)((n * BB + b) * 256) + (gid & 255)];
        yt[(size_t)b * 4096 + gid] = fmaf((v - mu) * rs, gg, bb);
    }
}

// ---------------------------------------------------------------------------
// og head via MFMA split-K GEMM + fused og-BN + target write.
// ---------------------------------------------------------------------------
__launch_bounds__(256)
__global__ void og_mm_ker(const float* __restrict__ yt, const float* __restrict__ lin_w,
                          void* __restrict__ d_out, const int* __restrict__ flag)
{
    __shared__ float part[4][32][17];   // [wave][batch][col], +1 pad
    const int tid = threadIdx.x;
    const int wv = tid >> 6;            // K-shard of 1024
    const int lane = tid & 63;
    const int qq = lane >> 4;           // K-subgroup of 8 within a 32-chunk
    const int ln = lane & 15;
    const int j0 = blockIdx.x * 16;

    const float* wrow  = lin_w + (size_t)(j0 + ln) * 4096 + wv * 1024;
    const float* yrow0 = yt + (size_t)ln * 4096 + wv * 1024;
    const float* yrow1 = yt + (size_t)(16 + ln) * 4096 + wv * 1024;

    f32x4v acc0 = {0.f, 0.f, 0.f, 0.f}, acc1 = {0.f, 0.f, 0.f, 0.f};
    for (int kc = 0; kc < 32; ++kc) {
        const int ko = kc * 32 + qq * 8;
        bf16x8v Bf = pack8(*(const float4*)(wrow + ko), *(const float4*)(wrow + ko + 4));
        bf16x8v A0 = pack8(*(const float4*)(yrow0 + ko), *(const float4*)(yrow0 + ko + 4));
        bf16x8v A1 = pack8(*(const float4*)(yrow1 + ko), *(const float4*)(yrow1 + ko + 4));
        acc0 = __builtin_amdgcn_mfma_f32_16x16x32_bf16(A0, Bf, acc0, 0, 0, 0);
        acc1 = __builtin_amdgcn_mfma_f32_16x16x32_bf16(A1, Bf, acc1, 0, 0, 0);
    }
    #pragma unroll
    for (int r = 0; r < 4; ++r) {
        part[wv][qq * 4 + r][ln]      = acc0[r];
        part[wv][16 + qq * 4 + r][ln] = acc1[r];
    }
    __syncthreads();

    if (tid < 16) {
        float vsum = 0.f, vsq = 0.f;
        for (int b = 0; b < BB; ++b) {
            float v = part[0][b][tid] + part[1][b][tid] + part[2][b][tid] + part[3][b][tid];
            vsum += v; vsq = fmaf(v, v, vsq);
        }
        float mu = vsum * (1.f / BB);
        float var = fmaxf(vsq * (1.f / BB) - mu * mu, 0.f);
        float rs = rsqrtf(var + 1e-5f);
        const int j = j0 + tid;
        const bool isf32 = (*flag != 0);
        for (int b = 0; b < BB; ++b) {
            float v = part[0][b][tid] + part[1][b][tid] + part[2][b][tid] + part[3][b][tid];
            float o = (v - mu) * rs;
            if (isf32) ((float*)d_out)[b * 256 + j] = o;
            else       ((bf16*)d_out)[b * 256 + j] = f2b(o);
        }
        float t = (float)(j & 15);
        if (isf32) { ((float*)d_out)[16384 + j] = t; ((float*)d_out)[16640 + j] = t; }
        else       { ((bf16*)d_out)[16384 + j] = f2b(t); ((bf16*)d_out)[16640 + j] = f2b(t); }
    }
}

// ---------------------------------------------------------------------------
// pred head
// ---------------------------------------------------------------------------
__launch_bounds__(256)
__global__ void pred_ker(const float* __restrict__ yt, const float* __restrict__ jig_w,
                         const float* __restrict__ jig_b, void* __restrict__ d_out,
                         const int* __restrict__ flag)
{
    __shared__ float sy[256];
    const int b = blockIdx.x >> 4, n = blockIdx.x & 15;
    sy[threadIdx.x] = yt[(size_t)b * 4096 + n * 256 + threadIdx.x];
    __syncthreads();
    const int k = threadIdx.x >> 4, part = threadIdx.x & 15;
    const float* wrow = jig_w + k * 256 + part * 16;
    const float* srow = sy + part * 16;
    float p = 0.f;
    #pragma unroll
    for (int t = 0; t < 16; ++t) p = fmaf(srow[t], wrow[t], p);
    #pragma unroll
    for (int off = 8; off > 0; off >>= 1) p += __shfl_down(p, off, 16);
    if (part == 0) {
        float v = p + jig_b[k];
        int pidx = 8192 + (b * 16 + n) * 16 + k;
        if (*flag) ((float*)d_out)[pidx] = v;
        else       ((bf16*)d_out)[pidx] = f2b(v);
    }
}

// ---------------------------------------------------------------------------
extern "C" void kernel_launch(void* const* d_in, const int* in_sizes, int n_in,
                              void* d_out, int out_size, void* d_ws, size_t ws_size,
                              hipStream_t stream)
{
    char* wsb = (char*)d_ws;
    int*   flag   = (int*)wsb;                      // @0
    float* y      = (float*)(wsb + 131072);         // 131072 f
    float* yt     = (float*)(wsb + 655360);         // 131072 f  [B][4096]
    bf16*  wtb    = (bf16*)(wsb + 1310720);         // packed bf16 MFMA weights (2.33MB)
    float* accumZ = (float*)(wsb + 3670016);        // sharded stats: 114688 f = 448KB
    float* staged = (float*)(wsb + 6029312);        // f32 arena

    // sharded accumulators: per stage NSH shards x [2][NN*C]
    float* A0 = accumZ + 0;       // C=16: 16*2*256 = 8192 f
    float* A1 = accumZ + 8192;    // C=16: 8192 f
    float* A2 = accumZ + 16384;   // C=32: 16384 f
    float* A3 = accumZ + 32768;   // C=32: 16384 f
    float* A4 = accumZ + 49152;   // C=64: 32768 f
    float* A5 = accumZ + 81920;   // C=64: 32768 f  (end 114688 f)

    bf16* wt1b = wtb;                    // 16*5*4*16*8  = 40960
    bf16* wt2b = wt1b + 40960;           // 16*5*4*32*8  = 81920
    bf16* wt3b = wt2b + 81920;           // 16*9*4*32*8  = 147456
    bf16* wt4b = wt3b + 147456;          // 16*9*4*64*8  = 294912
    bf16* wt5b = wt4b + 294912;          // 16*18*4*64*8 = 589824

    CvtArgs ca;
    int off = 0, maxc = 0;
    for (int i = 0; i < 19; ++i) {
        ca.src[i] = d_in[i];
        ca.cnt[i] = in_sizes[i];
        ca.off[i] = off;
        off += in_sizes[i];
        if (in_sizes[i] > maxc) maxc = in_sizes[i];
    }
    float* sx      = staged + ca.off[0];
    float* scw0    = staged + ca.off[1];
    float* shw1    = staged + ca.off[2];
    float* scw1    = staged + ca.off[3];
    float* shw2    = staged + ca.off[4];
    float* scw2    = staged + ca.off[5];
    float* shw3    = staged + ca.off[6];
    float* scw3    = staged + ca.off[7];
    float* shw4    = staged + ca.off[8];
    float* scw4    = staged + ca.off[9];
    float* shw5    = staged + ca.off[10];
    float* scw5    = staged + ca.off[11];
    float* spool   = staged + ca.off[12];
    float* sg      = staged + ca.off[13];
    float* sb      = staged + ca.off[14];
    float* slin_w  = staged + ca.off[15];
    float* slin_b  = staged + ca.off[16];
    float* sjig_w  = staged + ca.off[17];
    float* sjig_b  = staged + ca.off[18];
    (void)slin_b;  // BN-invariant, unused

    size_t stagedEnd = 6029312ull + (size_t)off * 4ull;
    size_t r1off = (stagedEnd + (1ull << 20)) & ~((1ull << 20) - 1ull);

    hipMemsetAsync(flag, 0, 4, stream);
    detect_ker<<<32, 256, 0, stream>>>((const uint4*)d_in[0], flag);
    convert_ker<<<dim3((maxc + 2047) / 2048, 19), 256, 0, stream>>>(ca, staged, flag);

    WpArgs wp;
    wp.src[0] = scw1; wp.dst[0] = wt1b; wp.cout[0] = 16; wp.cin[0] = 16; wp.nk[0] = 5;  wp.tot[0] = 16*5*4*16*8;
    wp.src[1] = scw2; wp.dst[1] = wt2b; wp.cout[1] = 32; wp.cin[1] = 16; wp.nk[1] = 5;  wp.tot[1] = 16*5*4*32*8;
    wp.src[2] = scw3; wp.dst[2] = wt3b; wp.cout[2] = 32; wp.cin[2] = 32; wp.nk[2] = 9;  wp.tot[2] = 16*9*4*32*8;
    wp.src[3] = scw4; wp.dst[3] = wt4b; wp.cout[3] = 64; wp.cin[3] = 32; wp.nk[3] = 9;  wp.tot[3] = 16*9*4*64*8;
    wp.src[4] = scw5; wp.dst[4] = wt5b; wp.cout[4] = 64; wp.cin[4] = 64; wp.nk[4] = 18; wp.tot[4] = 16*18*4*64*8;
    wprep_ker<<<dim3(2304, 5), 256, 0, stream>>>(wp);

    hipMemsetAsync(accumZ, 0, 114688 * sizeof(float), stream);

    // activation ping-pong: two 64 MiB regions (all activations bf16 NHWC)
    char* rA = wsb + r1off;
    char* rB = wsb + r1off + (64ull << 20);
    bf16* a0 = (bf16*)rB;
    bf16* a1 = (bf16*)rA;
    bf16* a2 = (bf16*)rB;
    bf16* a3 = (bf16*)rA;
    bf16* a4 = (bf16*)rB;
    bf16* a5 = (bf16*)rA;

    conv0w_ker<<<NN * BB * 8, 256, 0, stream>>>(sx, scw0, a0, A0);
    mconv_ker<16, 16, 64, 1, 8, 0, 1, false><<<NN * BB * 8, 256, 0, stream>>>(a0, A0, shw1, wt1b, a1, A1);
    mconv_ker<16, 32, 64, 2, 8, 0, 1, false><<<NN * BB * 4, 256, 0, stream>>>(a1, A1, shw2, wt2b, a2, A2);
    mconv_ker<32, 32, 32, 1, 8, 3, 3, false><<<NN * BB * 4, 256, 0, stream>>>(a2, A2, shw3, wt3b, a3, A3);
    mconv_ker<32, 64, 32, 2, 8, 3, 3, false><<<NN * BB * 2, 256, 0, stream>>>(a3, A3, shw4, wt4b, a4, A4);
    mconv_ker<64, 64, 16, 1, 16, 6, 3, true><<<dim3(NN * BB, 4), 256, 0, stream>>>(a4, A4, shw5, wt5b, a5, A5);
    pool_ker<<<NN * BB, 256, 0, stream>>>(a5, A5, spool, y);

    bn1_ker<<<NN, 256, 0, stream>>>(y, sg, sb, yt);
    og_mm_ker<<<16, 256, 0, stream>>>(yt, slin_w, d_out, flag);
    pred_ker<<<BB * NN, 256, 0, stream>>>(yt, sjig_w, sjig_b, d_out, flag);
}